// Round 2
// baseline (20827.336 us; speedup 1.0000x reference)
//
#include <hip/hip_runtime.h>
#include <cmath>

#define B_   64
#define T_   512
#define IN_  256
#define H_   512
#define OUT_ 256
#define M_   (B_*T_)   // 32768 rows for the input-projection GEMMs

typedef __bf16 bf16x4 __attribute__((ext_vector_type(4)));
typedef __bf16 bf16x8 __attribute__((ext_vector_type(8)));
typedef float  f32x4  __attribute__((ext_vector_type(4)));

// Split fp32 into bf16 hi (truncated, exact) + bf16 lo (RN of remainder).
static __device__ __forceinline__ void split_f32(float x, __bf16 &hi, __bf16 &lo) {
    unsigned u  = __float_as_uint(x);
    unsigned hu = u & 0xffff0000u;
    hi = __builtin_bit_cast(__bf16, (unsigned short)(hu >> 16));
    lo = (__bf16)(x - __uint_as_float(hu));
}

// ---------------- weight prep ----------------
__global__ void split_arr(const float* __restrict__ src, __bf16* __restrict__ hi,
                          __bf16* __restrict__ lo, int n) {
    int i = blockIdx.x * 256 + threadIdx.x;
    if (i < n) { __bf16 h, l; split_f32(src[i], h, l); hi[i] = h; lo[i] = l; }
}

__global__ void bias_comb(const float* __restrict__ a, const float* __restrict__ b,
                          float* __restrict__ o, int n) {
    int i = blockIdx.x * 256 + threadIdx.x;
    if (i < n) o[i] = a[i] + b[i];
}

// ---------------- xp GEMM: C[M,512] = A[M,K](f32) @ W[512,K]^T + bias ----------------
#define GBM 128
#define GBN 64
#define GBK 32
#define LDA 40

__global__ __launch_bounds__(256) void gemm_xp(
    const float* __restrict__ A, const __bf16* __restrict__ Whi,
    const __bf16* __restrict__ Wlo, const float* __restrict__ bias,
    float* __restrict__ C, int K)
{
    __shared__ __bf16 sAhi[GBM*LDA], sAlo[GBM*LDA], sBhi[GBN*LDA], sBlo[GBN*LDA];
    const int tid = threadIdx.x;
    const int m0 = blockIdx.y * GBM, n0 = blockIdx.x * GBN;
    const int wave = tid >> 6, lane = tid & 63, lm = lane & 15, q = lane >> 4;

    f32x4 acc[2][4];
#pragma unroll
    for (int i = 0; i < 2; ++i)
#pragma unroll
        for (int j = 0; j < 4; ++j) acc[i][j] = (f32x4){0.f,0.f,0.f,0.f};

    for (int k0 = 0; k0 < K; k0 += GBK) {
        __syncthreads();
#pragma unroll
        for (int i = 0; i < 4; ++i) {
            int c = tid + i * 256;
            int row = c >> 3, pos = c & 7;
            float4 v = *(const float4*)(&A[(size_t)(m0+row)*K + k0 + pos*4]);
            __bf16 h0,l0,h1,l1,h2,l2,h3,l3;
            split_f32(v.x,h0,l0); split_f32(v.y,h1,l1);
            split_f32(v.z,h2,l2); split_f32(v.w,h3,l3);
            *(bf16x4*)(&sAhi[row*LDA + pos*4]) = (bf16x4){h0,h1,h2,h3};
            *(bf16x4*)(&sAlo[row*LDA + pos*4]) = (bf16x4){l0,l1,l2,l3};
        }
        {
            int row = tid >> 2, pos = (tid & 3) * 8;
            *(bf16x8*)(&sBhi[row*LDA + pos]) =
                *(const bf16x8*)(&Whi[(size_t)(n0+row)*K + k0 + pos]);
            *(bf16x8*)(&sBlo[row*LDA + pos]) =
                *(const bf16x8*)(&Wlo[(size_t)(n0+row)*K + k0 + pos]);
        }
        __syncthreads();

        bf16x8 ah[2], al[2], bh[4], bl[4];
#pragma unroll
        for (int mt = 0; mt < 2; ++mt) {
            int r = wave*32 + mt*16 + lm;
            ah[mt] = *(const bf16x8*)(&sAhi[r*LDA + q*8]);
            al[mt] = *(const bf16x8*)(&sAlo[r*LDA + q*8]);
        }
#pragma unroll
        for (int nt = 0; nt < 4; ++nt) {
            int r = nt*16 + lm;
            bh[nt] = *(const bf16x8*)(&sBhi[r*LDA + q*8]);
            bl[nt] = *(const bf16x8*)(&sBlo[r*LDA + q*8]);
        }
#pragma unroll
        for (int mt = 0; mt < 2; ++mt)
#pragma unroll
            for (int nt = 0; nt < 4; ++nt) {
                acc[mt][nt] = __builtin_amdgcn_mfma_f32_16x16x32_bf16(ah[mt], bh[nt], acc[mt][nt], 0,0,0);
                acc[mt][nt] = __builtin_amdgcn_mfma_f32_16x16x32_bf16(ah[mt], bl[nt], acc[mt][nt], 0,0,0);
                acc[mt][nt] = __builtin_amdgcn_mfma_f32_16x16x32_bf16(al[mt], bh[nt], acc[mt][nt], 0,0,0);
            }
    }
#pragma unroll
    for (int mt = 0; mt < 2; ++mt)
#pragma unroll
        for (int nt = 0; nt < 4; ++nt)
#pragma unroll
            for (int r = 0; r < 4; ++r) {
                int m = m0 + wave*32 + mt*16 + q*4 + r;
                int n = n0 + nt*16 + lm;
                C[(size_t)m*H_ + n] = acc[mt][nt][r] + bias[n];
            }
}

// ---------------- recurrence: batch-split, zero inter-block communication ----------------
// 4 blocks x 1024 threads (16 waves). Block g owns batch rows 16g..16g+15 for
// all T steps. W_hh hi/lo pre-split, held in REGISTERS as MFMA B-fragments
// (wave w owns output cols 32w..32w+31 -> 256 VGPRs/thread). h lives in LDS
// (hi/lo bf16, stride 520: 16B-aligned b128 reads, 2-way banks = free).
// Per step: 2 __syncthreads, no fences, no global h traffic.
#define LDH 520

__global__ __launch_bounds__(1024) void rnn_rec(
    const float* __restrict__ xp,                        // [B,T,H] fp32
    const __bf16* __restrict__ Whi, const __bf16* __restrict__ Wlo,  // [H,H]
    float* __restrict__ out_seq,                         // [B,T,H] or null
    float* __restrict__ out_last)                        // [B,H] or null
{
    __shared__ __bf16 sHhi[16*LDH], sHlo[16*LDH];
    const int tid  = threadIdx.x;
    const int wave = tid >> 6, lane = tid & 63, lm = lane & 15, q = lane >> 4;
    const int m0 = blockIdx.x * 16;    // batch rows owned by this block
    const int n0 = wave * 32;          // output cols owned by this wave

    // W_hh B-fragments: B[k][n] = W[n][k]; lane holds W[n0+nt*16+lm][kt*32+q*8 ..+7]
    bf16x8 Bh[2][16], Bl[2][16];
#pragma unroll
    for (int nt = 0; nt < 2; ++nt)
#pragma unroll
        for (int kt = 0; kt < 16; ++kt) {
            const size_t n = n0 + nt*16 + lm;
            Bh[nt][kt] = *(const bf16x8*)(&Whi[n*H_ + kt*32 + q*8]);
            Bl[nt][kt] = *(const bf16x8*)(&Wlo[n*H_ + kt*32 + q*8]);
        }
    for (int i = tid; i < 16*LDH; i += 1024) { sHhi[i] = (__bf16)0.f; sHlo[i] = (__bf16)0.f; }
    __syncthreads();

    for (int t = 0; t < T_; ++t) {
        // stream xp for this step; issued before the MFMA chain to hide HBM latency
        float xv[2][4];
#pragma unroll
        for (int nt = 0; nt < 2; ++nt)
#pragma unroll
            for (int r = 0; r < 4; ++r)
                xv[nt][r] = xp[((size_t)(m0 + q*4 + r)*T_ + t)*H_ + n0 + nt*16 + lm];

        f32x4 acc[2];
        acc[0] = (f32x4){0.f,0.f,0.f,0.f};
        acc[1] = (f32x4){0.f,0.f,0.f,0.f};
#pragma unroll
        for (int kt = 0; kt < 16; ++kt) {
            bf16x8 ah = *(const bf16x8*)(&sHhi[lm*LDH + kt*32 + q*8]);
            bf16x8 al = *(const bf16x8*)(&sHlo[lm*LDH + kt*32 + q*8]);
#pragma unroll
            for (int nt = 0; nt < 2; ++nt) {
                acc[nt] = __builtin_amdgcn_mfma_f32_16x16x32_bf16(ah, Bh[nt][kt], acc[nt], 0,0,0);
                acc[nt] = __builtin_amdgcn_mfma_f32_16x16x32_bf16(ah, Bl[nt][kt], acc[nt], 0,0,0);
                acc[nt] = __builtin_amdgcn_mfma_f32_16x16x32_bf16(al, Bh[nt][kt], acc[nt], 0,0,0);
            }
        }
        __syncthreads();   // all reads of h_t complete before overwriting
#pragma unroll
        for (int nt = 0; nt < 2; ++nt)
#pragma unroll
            for (int r = 0; r < 4; ++r) {
                float v = xv[nt][r] + acc[nt][r];
                // tanh(v) = 1 - 2/(e^{2v}+1); abs err ~1e-7, handles +-inf saturation
                float e  = __expf(2.f*v);
                float hv = 1.f - 2.f/(e + 1.f);
                __bf16 hh, hl; split_f32(hv, hh, hl);
                int m = q*4 + r, n = n0 + nt*16 + lm;
                sHhi[m*LDH + n] = hh;
                sHlo[m*LDH + n] = hl;
                if (out_seq) out_seq[((size_t)(m0+m)*T_ + t)*H_ + n] = hv;
                if (out_last && t == T_-1) out_last[(size_t)(m0+m)*H_ + n] = hv;
            }
        __syncthreads();   // h_{t+1} visible to all waves
    }
}

// ---------------- output projection ----------------
__global__ __launch_bounds__(256) void out_proj(
    const float* __restrict__ hlast, const float* __restrict__ Wout,
    const float* __restrict__ bout, float* __restrict__ out)
{
    __shared__ float sh[H_];
    int b = blockIdx.x;
    for (int i = threadIdx.x; i < H_; i += 256) sh[i] = hlast[(size_t)b*H_ + i];
    __syncthreads();
    int o = threadIdx.x;
    const float* wr = &Wout[(size_t)o*H_];
    float acc = 0.f;
#pragma unroll 4
    for (int k = 0; k < H_; k += 4) {
        float4 wv = *(const float4*)(&wr[k]);
        acc += wv.x*sh[k] + wv.y*sh[k+1] + wv.z*sh[k+2] + wv.w*sh[k+3];
    }
    out[(size_t)b*OUT_ + o] = bout[o] + acc;
}

extern "C" void kernel_launch(void* const* d_in, const int* in_sizes, int n_in,
                              void* d_out, int out_size, void* d_ws, size_t ws_size,
                              hipStream_t stream)
{
    const float* x    = (const float*)d_in[0];
    const float* Wih0 = (const float*)d_in[1];
    const float* Whh0 = (const float*)d_in[2];
    const float* bih0 = (const float*)d_in[3];
    const float* bhh0 = (const float*)d_in[4];
    const float* Wih1 = (const float*)d_in[5];
    const float* Whh1 = (const float*)d_in[6];
    const float* bih1 = (const float*)d_in[7];
    const float* bhh1 = (const float*)d_in[8];
    const float* Wout = (const float*)d_in[9];
    const float* bout = (const float*)d_in[10];

    char* w = (char*)d_ws;
    size_t off = 0;
    auto alloc = [&](size_t bytes) -> void* {
        void* p = w + off; off = (off + bytes + 255) & ~(size_t)255; return p;
    };
    float*  xp     = (float*) alloc((size_t)M_*H_*4);
    float*  out0   = (float*) alloc((size_t)M_*H_*4);
    __bf16* wih0hi = (__bf16*)alloc((size_t)H_*IN_*2);
    __bf16* wih0lo = (__bf16*)alloc((size_t)H_*IN_*2);
    __bf16* whh0hi = (__bf16*)alloc((size_t)H_*H_*2);
    __bf16* whh0lo = (__bf16*)alloc((size_t)H_*H_*2);
    __bf16* wih1hi = (__bf16*)alloc((size_t)H_*H_*2);
    __bf16* wih1lo = (__bf16*)alloc((size_t)H_*H_*2);
    __bf16* whh1hi = (__bf16*)alloc((size_t)H_*H_*2);
    __bf16* whh1lo = (__bf16*)alloc((size_t)H_*H_*2);
    float*  bias0  = (float*) alloc(H_*4);
    float*  bias1  = (float*) alloc(H_*4);
    float*  hlast  = (float*) alloc((size_t)B_*H_*4);

    split_arr<<<(H_*IN_+255)/256, 256, 0, stream>>>(Wih0, wih0hi, wih0lo, H_*IN_);
    split_arr<<<(H_*H_ +255)/256, 256, 0, stream>>>(Whh0, whh0hi, whh0lo, H_*H_);
    split_arr<<<(H_*H_ +255)/256, 256, 0, stream>>>(Wih1, wih1hi, wih1lo, H_*H_);
    split_arr<<<(H_*H_ +255)/256, 256, 0, stream>>>(Whh1, whh1hi, whh1lo, H_*H_);
    bias_comb<<<2, 256, 0, stream>>>(bih0, bhh0, bias0, H_);
    bias_comb<<<2, 256, 0, stream>>>(bih1, bhh1, bias1, H_);

    dim3 ggrid(H_/GBN, M_/GBM);  // (8, 256)
    gemm_xp<<<ggrid, 256, 0, stream>>>(x, wih0hi, wih0lo, bias0, xp, IN_);
    rnn_rec<<<4, 1024, 0, stream>>>(xp, whh0hi, whh0lo, out0, nullptr);
    gemm_xp<<<ggrid, 256, 0, stream>>>(out0, wih1hi, wih1lo, bias1, xp, H_);
    rnn_rec<<<4, 1024, 0, stream>>>(xp, whh1hi, whh1lo, nullptr, hlast);
    out_proj<<<B_, 256, 0, stream>>>(hlast, Wout, bout, (float*)d_out);
}

// Round 3
// 10391.293 us; speedup vs baseline: 2.0043x; 2.0043x over previous
//
#include <hip/hip_runtime.h>
#include <cmath>

#define B_   64
#define T_   512
#define IN_  256
#define H_   512
#define OUT_ 256
#define M_   (B_*T_)
#define RB   16      // recurrence blocks (barrier participants)

typedef __bf16 bf16x4 __attribute__((ext_vector_type(4)));
typedef __bf16 bf16x8 __attribute__((ext_vector_type(8)));
typedef float  f32x4  __attribute__((ext_vector_type(4)));

static __device__ __forceinline__ void split_f32(float x, __bf16 &hi, __bf16 &lo) {
    unsigned u  = __float_as_uint(x);
    unsigned hu = u & 0xffff0000u;
    hi = __builtin_bit_cast(__bf16, (unsigned short)(hu >> 16));
    lo = (__bf16)(x - __uint_as_float(hu));
}

// device-scope (sc1) store: write-around own L2 straight to the coherence
// point (IF$). This is how LLVM lowers agent-scope atomic stores; paired with
// s_waitcnt vmcnt(0) it gives release semantics without buffer_wbl2.
static __device__ __forceinline__ void store_short_sc1(__bf16* p, unsigned v) {
    asm volatile("global_store_short %0, %1, off sc1" :: "v"(p), "v"(v) : "memory");
}

// ---------------- weight prep ----------------
__global__ void split_arr(const float* __restrict__ src, __bf16* __restrict__ hi,
                          __bf16* __restrict__ lo, int n) {
    int i = blockIdx.x * 256 + threadIdx.x;
    if (i < n) { __bf16 h, l; split_f32(src[i], h, l); hi[i] = h; lo[i] = l; }
}

__global__ void bias_comb(const float* __restrict__ a, const float* __restrict__ b,
                          float* __restrict__ o, int n) {
    int i = blockIdx.x * 256 + threadIdx.x;
    if (i < n) o[i] = a[i] + b[i];
}

// ---------------- xp GEMM (fp32 A): C[M,512] = A @ W^T + bias ----------------
#define GBM 128
#define GBN 64
#define GBK 32
#define LDA 40

__global__ __launch_bounds__(256) void gemm_xp(
    const float* __restrict__ A, const __bf16* __restrict__ Whi,
    const __bf16* __restrict__ Wlo, const float* __restrict__ bias,
    float* __restrict__ C, int K)
{
    __shared__ __bf16 sAhi[GBM*LDA], sAlo[GBM*LDA], sBhi[GBN*LDA], sBlo[GBN*LDA];
    const int tid = threadIdx.x;
    const int m0 = blockIdx.y * GBM, n0 = blockIdx.x * GBN;
    const int wave = tid >> 6, lane = tid & 63, lm = lane & 15, q = lane >> 4;

    f32x4 acc[2][4];
#pragma unroll
    for (int i = 0; i < 2; ++i)
#pragma unroll
        for (int j = 0; j < 4; ++j) acc[i][j] = (f32x4){0.f,0.f,0.f,0.f};

    for (int k0 = 0; k0 < K; k0 += GBK) {
        __syncthreads();
#pragma unroll
        for (int i = 0; i < 4; ++i) {
            int c = tid + i * 256;
            int row = c >> 3, pos = c & 7;
            float4 v = *(const float4*)(&A[(size_t)(m0+row)*K + k0 + pos*4]);
            __bf16 h0,l0,h1,l1,h2,l2,h3,l3;
            split_f32(v.x,h0,l0); split_f32(v.y,h1,l1);
            split_f32(v.z,h2,l2); split_f32(v.w,h3,l3);
            *(bf16x4*)(&sAhi[row*LDA + pos*4]) = (bf16x4){h0,h1,h2,h3};
            *(bf16x4*)(&sAlo[row*LDA + pos*4]) = (bf16x4){l0,l1,l2,l3};
        }
        {
            int row = tid >> 2, pos = (tid & 3) * 8;
            *(bf16x8*)(&sBhi[row*LDA + pos]) =
                *(const bf16x8*)(&Whi[(size_t)(n0+row)*K + k0 + pos]);
            *(bf16x8*)(&sBlo[row*LDA + pos]) =
                *(const bf16x8*)(&Wlo[(size_t)(n0+row)*K + k0 + pos]);
        }
        __syncthreads();

        bf16x8 ah[2], al[2], bh[4], bl[4];
#pragma unroll
        for (int mt = 0; mt < 2; ++mt) {
            int r = wave*32 + mt*16 + lm;
            ah[mt] = *(const bf16x8*)(&sAhi[r*LDA + q*8]);
            al[mt] = *(const bf16x8*)(&sAlo[r*LDA + q*8]);
        }
#pragma unroll
        for (int nt = 0; nt < 4; ++nt) {
            int r = nt*16 + lm;
            bh[nt] = *(const bf16x8*)(&sBhi[r*LDA + q*8]);
            bl[nt] = *(const bf16x8*)(&sBlo[r*LDA + q*8]);
        }
#pragma unroll
        for (int mt = 0; mt < 2; ++mt)
#pragma unroll
            for (int nt = 0; nt < 4; ++nt) {
                acc[mt][nt] = __builtin_amdgcn_mfma_f32_16x16x32_bf16(ah[mt], bh[nt], acc[mt][nt], 0,0,0);
                acc[mt][nt] = __builtin_amdgcn_mfma_f32_16x16x32_bf16(ah[mt], bl[nt], acc[mt][nt], 0,0,0);
                acc[mt][nt] = __builtin_amdgcn_mfma_f32_16x16x32_bf16(al[mt], bh[nt], acc[mt][nt], 0,0,0);
            }
    }
#pragma unroll
    for (int mt = 0; mt < 2; ++mt)
#pragma unroll
        for (int nt = 0; nt < 4; ++nt)
#pragma unroll
            for (int r = 0; r < 4; ++r) {
                int m = m0 + wave*32 + mt*16 + q*4 + r;
                int n = n0 + nt*16 + lm;
                C[(size_t)m*H_ + n] = acc[mt][nt][r] + bias[n];
            }
}

// ---------------- xp GEMM (packed hi|lo A from layer-0 output) ----------------
__global__ __launch_bounds__(256) void gemm_xp_pk(
    const uint32_t* __restrict__ Ap, const __bf16* __restrict__ Whi,
    const __bf16* __restrict__ Wlo, const float* __restrict__ bias,
    float* __restrict__ C, int K)
{
    __shared__ __bf16 sAhi[GBM*LDA], sAlo[GBM*LDA], sBhi[GBN*LDA], sBlo[GBN*LDA];
    const int tid = threadIdx.x;
    const int m0 = blockIdx.y * GBM, n0 = blockIdx.x * GBN;
    const int wave = tid >> 6, lane = tid & 63, lm = lane & 15, q = lane >> 4;

    f32x4 acc[2][4];
#pragma unroll
    for (int i = 0; i < 2; ++i)
#pragma unroll
        for (int j = 0; j < 4; ++j) acc[i][j] = (f32x4){0.f,0.f,0.f,0.f};

    for (int k0 = 0; k0 < K; k0 += GBK) {
        __syncthreads();
#pragma unroll
        for (int i = 0; i < 4; ++i) {
            int c = tid + i * 256;              // 1024 uint4 chunks (4 elems each)
            int row = c >> 3, pos = c & 7;
            uint4 dv = *(const uint4*)(&Ap[(size_t)(m0+row)*K + k0 + pos*4]);
            uint32_t h01 = __builtin_amdgcn_perm(dv.y, dv.x, 0x07060302);
            uint32_t h23 = __builtin_amdgcn_perm(dv.w, dv.z, 0x07060302);
            uint32_t l01 = __builtin_amdgcn_perm(dv.y, dv.x, 0x05040100);
            uint32_t l23 = __builtin_amdgcn_perm(dv.w, dv.z, 0x05040100);
            *(uint2*)(&sAhi[row*LDA + pos*4]) = make_uint2(h01, h23);
            *(uint2*)(&sAlo[row*LDA + pos*4]) = make_uint2(l01, l23);
        }
        {
            int row = tid >> 2, pos = (tid & 3) * 8;
            *(bf16x8*)(&sBhi[row*LDA + pos]) =
                *(const bf16x8*)(&Whi[(size_t)(n0+row)*K + k0 + pos]);
            *(bf16x8*)(&sBlo[row*LDA + pos]) =
                *(const bf16x8*)(&Wlo[(size_t)(n0+row)*K + k0 + pos]);
        }
        __syncthreads();

        bf16x8 ah[2], al[2], bh[4], bl[4];
#pragma unroll
        for (int mt = 0; mt < 2; ++mt) {
            int r = wave*32 + mt*16 + lm;
            ah[mt] = *(const bf16x8*)(&sAhi[r*LDA + q*8]);
            al[mt] = *(const bf16x8*)(&sAlo[r*LDA + q*8]);
        }
#pragma unroll
        for (int nt = 0; nt < 4; ++nt) {
            int r = nt*16 + lm;
            bh[nt] = *(const bf16x8*)(&sBhi[r*LDA + q*8]);
            bl[nt] = *(const bf16x8*)(&sBlo[r*LDA + q*8]);
        }
#pragma unroll
        for (int mt = 0; mt < 2; ++mt)
#pragma unroll
            for (int nt = 0; nt < 4; ++nt) {
                acc[mt][nt] = __builtin_amdgcn_mfma_f32_16x16x32_bf16(ah[mt], bh[nt], acc[mt][nt], 0,0,0);
                acc[mt][nt] = __builtin_amdgcn_mfma_f32_16x16x32_bf16(ah[mt], bl[nt], acc[mt][nt], 0,0,0);
                acc[mt][nt] = __builtin_amdgcn_mfma_f32_16x16x32_bf16(al[mt], bh[nt], acc[mt][nt], 0,0,0);
            }
    }
#pragma unroll
    for (int mt = 0; mt < 2; ++mt)
#pragma unroll
        for (int nt = 0; nt < 4; ++nt)
#pragma unroll
            for (int r = 0; r < 4; ++r) {
                int m = m0 + wave*32 + mt*16 + q*4 + r;
                int n = n0 + nt*16 + lm;
                C[(size_t)m*H_ + n] = acc[mt][nt][r] + bias[n];
            }
}

// ---------------- recurrence: column-split, sc1-store / buffer_inv protocol ----------------
// 16 blocks x 512 threads. Block owns 32 output cols; W slice hi/lo in 64 KB
// LDS, XOR-swizzled (k-chunk c stored at c ^ (col&7) -> conflict-free b128).
// h double-buffered in global as separate hi/lo bf16 arrays.
//   producer: sc1 short stores (write-around L2 to IF$) -> s_waitcnt 0 ->
//             __syncthreads -> tid0 relaxed agent atomic add
//   consumer: tid0 spins on counter -> __syncthreads -> buffer_inv sc1
//             (agent-acquire: invalidate L1 + clean L2-NC lines) -> plain
//             coalesced dwordx4 loads refill from IF$.
__global__ __launch_bounds__(512) void rnn_rec_cs(
    const float* __restrict__ xp,                        // [B,T,H] fp32
    const __bf16* __restrict__ Whi, const __bf16* __restrict__ Wlo,  // [H,H]
    __bf16* __restrict__ hhi, __bf16* __restrict__ hlo,  // [2][B,H], buf0 zeroed
    uint32_t* __restrict__ outp,                         // [B,T,H] packed or null
    float* __restrict__ olast,                           // [B,H] or null
    int* __restrict__ bar)                               // zeroed
{
    __shared__ __bf16 sWhi[32*512], sWlo[32*512];        // 64 KB total
    const int tid = threadIdx.x;
    const int n0 = blockIdx.x * 32;

    // stage W slice with XOR swizzle on 8-elem chunks
#pragma unroll
    for (int i = 0; i < 4; ++i) {
        int cl = tid + i*512;                 // 0..2047
        int j = cl >> 6, c = cl & 63;
        int dst = (j*64 + (c ^ (j & 7))) * 8;
        *(bf16x8*)(&sWhi[dst]) = *(const bf16x8*)(&Whi[(size_t)(n0+j)*H_ + c*8]);
        *(bf16x8*)(&sWlo[dst]) = *(const bf16x8*)(&Wlo[(size_t)(n0+j)*H_ + c*8]);
    }
    __syncthreads();

    const int wave = tid >> 6, lane = tid & 63, lm = lane & 15, q = lane >> 4;
    const int bg = wave & 3, cg = wave >> 2;
    const int jn = cg*16 + lm;                // local col (B-frag lane row)
    const int n  = n0 + jn;                   // global col
    const int arow = bg*16 + lm;              // A-frag row (batch)
    const int swz = jn & 7;

    float xv[4];
#pragma unroll
    for (int r = 0; r < 4; ++r)
        xv[r] = xp[((size_t)(bg*16 + q*4 + r)*T_ + 0)*H_ + n];

    for (int t = 0; t < T_; ++t) {
        const __bf16* shi = hhi + (size_t)(t & 1) * (B_*H_);
        const __bf16* slo = hlo + (size_t)(t & 1) * (B_*H_);
        __bf16* dhi = hhi + (size_t)((t+1) & 1) * (B_*H_);
        __bf16* dlo = hlo + (size_t)((t+1) & 1) * (B_*H_);

        f32x4 acc = (f32x4){0.f,0.f,0.f,0.f};
#pragma unroll
        for (int kt = 0; kt < 16; ++kt) {
            const int ko = kt*32 + q*8;
            bf16x8 ah = *(const bf16x8*)(&shi[(size_t)arow*H_ + ko]);
            bf16x8 al = *(const bf16x8*)(&slo[(size_t)arow*H_ + ko]);
            const int woff = (jn*64 + (((kt*4) + q) ^ swz)) * 8;
            bf16x8 bh = *(const bf16x8*)(&sWhi[woff]);
            bf16x8 bl = *(const bf16x8*)(&sWlo[woff]);
            acc = __builtin_amdgcn_mfma_f32_16x16x32_bf16(ah, bh, acc, 0,0,0);
            acc = __builtin_amdgcn_mfma_f32_16x16x32_bf16(ah, bl, acc, 0,0,0);
            acc = __builtin_amdgcn_mfma_f32_16x16x32_bf16(al, bh, acc, 0,0,0);
        }

#pragma unroll
        for (int r = 0; r < 4; ++r) {
            const int b = bg*16 + q*4 + r;
            float v = xv[r] + acc[r];
            float e  = __expf(2.f*v);
            float hv = 1.f - 2.f/(e + 1.f);
            unsigned u  = __float_as_uint(hv);
            unsigned hu = u & 0xffff0000u;
            unsigned short hh = (unsigned short)(hu >> 16);
            __bf16 hlb = (__bf16)(hv - __uint_as_float(hu));
            unsigned short hl = __builtin_bit_cast(unsigned short, hlb);
            store_short_sc1(&dhi[(size_t)b*H_ + n], hh);
            store_short_sc1(&dlo[(size_t)b*H_ + n], hl);
            if (outp) outp[((size_t)b*T_ + t)*H_ + n] = ((uint32_t)hh << 16) | hl;
            if (olast && t == T_-1) olast[(size_t)b*H_ + n] = hv;
        }

        if (t < T_-1) {
            __builtin_amdgcn_s_waitcnt(0);    // drain sc1 stores (wave-local)
            __syncthreads();                  // all waves of block drained
            if (tid == 0)
                __hip_atomic_fetch_add(bar, 1, __ATOMIC_RELAXED, __HIP_MEMORY_SCOPE_AGENT);
            // prefetch next step's xp during the spin (coherence-free data)
#pragma unroll
            for (int r = 0; r < 4; ++r)
                xv[r] = xp[((size_t)(bg*16 + q*4 + r)*T_ + (t+1))*H_ + n];
            if (tid == 0) {
                const int target = RB * (t + 1);
                while (__hip_atomic_load(bar, __ATOMIC_RELAXED, __HIP_MEMORY_SCOPE_AGENT) < target) {}
            }
            __syncthreads();
            asm volatile("buffer_inv sc1" ::: "memory");   // agent acquire
        }
    }
}

// ---------------- output projection ----------------
__global__ __launch_bounds__(256) void out_proj(
    const float* __restrict__ hlast, const float* __restrict__ Wout,
    const float* __restrict__ bout, float* __restrict__ out)
{
    __shared__ float sh[H_];
    int b = blockIdx.x;
    for (int i = threadIdx.x; i < H_; i += 256) sh[i] = hlast[(size_t)b*H_ + i];
    __syncthreads();
    int o = threadIdx.x;
    const float* wr = &Wout[(size_t)o*H_];
    float acc = 0.f;
#pragma unroll 4
    for (int k = 0; k < H_; k += 4) {
        float4 wv = *(const float4*)(&wr[k]);
        acc += wv.x*sh[k] + wv.y*sh[k+1] + wv.z*sh[k+2] + wv.w*sh[k+3];
    }
    out[(size_t)b*OUT_ + o] = bout[o] + acc;
}

extern "C" void kernel_launch(void* const* d_in, const int* in_sizes, int n_in,
                              void* d_out, int out_size, void* d_ws, size_t ws_size,
                              hipStream_t stream)
{
    const float* x    = (const float*)d_in[0];
    const float* Wih0 = (const float*)d_in[1];
    const float* Whh0 = (const float*)d_in[2];
    const float* bih0 = (const float*)d_in[3];
    const float* bhh0 = (const float*)d_in[4];
    const float* Wih1 = (const float*)d_in[5];
    const float* Whh1 = (const float*)d_in[6];
    const float* bih1 = (const float*)d_in[7];
    const float* bhh1 = (const float*)d_in[8];
    const float* Wout = (const float*)d_in[9];
    const float* bout = (const float*)d_in[10];

    char* w = (char*)d_ws;
    size_t off = 0;
    auto alloc = [&](size_t bytes) -> void* {
        void* p = w + off; off = (off + bytes + 255) & ~(size_t)255; return p;
    };
    float*    xp     = (float*)   alloc((size_t)M_*H_*4);   // 64 MB
    uint32_t* out0p  = (uint32_t*)alloc((size_t)M_*H_*4);   // 64 MB packed hi|lo
    __bf16* wih0hi = (__bf16*)alloc((size_t)H_*IN_*2);
    __bf16* wih0lo = (__bf16*)alloc((size_t)H_*IN_*2);
    __bf16* whh0hi = (__bf16*)alloc((size_t)H_*H_*2);
    __bf16* whh0lo = (__bf16*)alloc((size_t)H_*H_*2);
    __bf16* wih1hi = (__bf16*)alloc((size_t)H_*H_*2);
    __bf16* wih1lo = (__bf16*)alloc((size_t)H_*H_*2);
    __bf16* whh1hi = (__bf16*)alloc((size_t)H_*H_*2);
    __bf16* whh1lo = (__bf16*)alloc((size_t)H_*H_*2);
    float*  bias0  = (float*) alloc(H_*4);
    float*  bias1  = (float*) alloc(H_*4);
    float*  hlast  = (float*) alloc((size_t)B_*H_*4);
    size_t zstart = off;                                    // zero region
    __bf16* h0hi = (__bf16*)alloc((size_t)2*B_*H_*2);
    __bf16* h0lo = (__bf16*)alloc((size_t)2*B_*H_*2);
    __bf16* h1hi = (__bf16*)alloc((size_t)2*B_*H_*2);
    __bf16* h1lo = (__bf16*)alloc((size_t)2*B_*H_*2);
    int*    bars = (int*)   alloc(256);
    size_t zlen = off - zstart;
    int* bar0 = bars, *bar1 = bars + 32;

    hipMemsetAsync(w + zstart, 0, zlen, stream);

    split_arr<<<(H_*IN_+255)/256, 256, 0, stream>>>(Wih0, wih0hi, wih0lo, H_*IN_);
    split_arr<<<(H_*H_ +255)/256, 256, 0, stream>>>(Whh0, whh0hi, whh0lo, H_*H_);
    split_arr<<<(H_*H_ +255)/256, 256, 0, stream>>>(Wih1, wih1hi, wih1lo, H_*H_);
    split_arr<<<(H_*H_ +255)/256, 256, 0, stream>>>(Whh1, whh1hi, whh1lo, H_*H_);
    bias_comb<<<2, 256, 0, stream>>>(bih0, bhh0, bias0, H_);
    bias_comb<<<2, 256, 0, stream>>>(bih1, bhh1, bias1, H_);

    dim3 ggrid(H_/GBN, M_/GBM);  // (8, 256)
    gemm_xp<<<ggrid, 256, 0, stream>>>(x, wih0hi, wih0lo, bias0, xp, IN_);
    rnn_rec_cs<<<RB, 512, 0, stream>>>(xp, whh0hi, whh0lo, h0hi, h0lo, out0p, nullptr, bar0);
    gemm_xp_pk<<<ggrid, 256, 0, stream>>>(out0p, wih1hi, wih1lo, bias1, xp, H_);
    rnn_rec_cs<<<RB, 512, 0, stream>>>(xp, whh1hi, whh1lo, h1hi, h1lo, nullptr, hlast, bar1);
    out_proj<<<B_, 256, 0, stream>>>(hlast, Wout, bout, (float*)d_out);
}